// Round 8
// baseline (161.819 us; speedup 1.0000x reference)
//
#include <hip/hip_runtime.h>
#include <cstdint>

// ---------------------------------------------------------------------------
// QuantumCoherentLayer collapsed:
//   out[b,h2] = sum_p wHI[p]*coh[b,p,h2] + (x @ Win @ WeffLO)[b,h2]
//   w[j] = (alpha/64)*colsum_j(softmax_rows(cos(phase*J_sym)))
//   wLO = w*(1-alpha) folded into Weff; wHI = w*alpha.
// Frag order: slot = ((rt*32+kt)*64+lane)*8 shorts; lane=(row%16)+16*((k%32)/8)
// holds k%8..+7 (m89-verified; same for A and B operands).
// R8: drop ALL nontemporal hints. The harness's per-iteration d_in restore
// leaves inputs hot in the 256 MiB L3 (R3 counters: FETCH 55 MB vs 108 MB
// read = ~50% L3 hits); nt loads were bypassing that and forcing full-latency
// HBM reads on every stream. Structure otherwise identical to R7.
// ---------------------------------------------------------------------------

typedef __attribute__((ext_vector_type(8))) __bf16 bf16x8;
typedef __attribute__((ext_vector_type(4))) float f32x4;
typedef unsigned short u16;

__device__ __forceinline__ u16 f32_to_bf16_rne(float f) {
  unsigned int u = __float_as_uint(f);
  u += 0x7fffu + ((u >> 16) & 1u);
  return (u16)(u >> 16);
}

__device__ __forceinline__ f32x4 ld4(const float* p) {
  return *(const f32x4*)p;  // cached load — inputs are L3-hot from restore
}

// Per-wave scalars; lane ends with w for j=(lane&7), plus alpha.
__device__ __forceinline__ void wave_scalars(const float* __restrict__ J,
                                             const float* __restrict__ t,
                                             float* w_out, float* alpha_out) {
  const int lane = threadIdx.x & 63;
  float tv = t[0];
  float alpha = fminf(fmaxf(expf(-tv / 51.0f), 0.0f), 1.0f);
  float phase = 2.0f * 3.14159265358979323846f * 20.0f * tv / 1000.0f;
  int i = lane >> 3, j = lane & 7;
  float jsym = 0.5f * (J[i * 8 + j] + J[j * 8 + i]);
  float e = expf(cosf(phase * jsym));
  float rs = e;
  rs += __shfl_xor(rs, 1);
  rs += __shfl_xor(rs, 2);
  rs += __shfl_xor(rs, 4);
  float p = e / rs;
  float cs = p;
  cs += __shfl_xor(cs, 8);
  cs += __shfl_xor(cs, 16);
  cs += __shfl_xor(cs, 32);
  *w_out = alpha * (1.0f / 64.0f) * cs;
  *alpha_out = alpha;
}

// fp32 [16 rows x 1024] -> bf16 frag via LDS tile (256 threads)
__device__ __forceinline__ void convert16(const float* __restrict__ src,
                                          u16* __restrict__ dst, u16* ld,
                                          int tid) {
  f32x4 v[16];
#pragma unroll
  for (int row = 0; row < 16; row++) v[row] = ld4(src + row * 1024 + tid * 4);
#pragma unroll
  for (int row = 0; row < 16; row++) {
    ushort4 o;
    o.x = f32_to_bf16_rne(v[row][0]);
    o.y = f32_to_bf16_rne(v[row][1]);
    o.z = f32_to_bf16_rne(v[row][2]);
    o.w = f32_to_bf16_rne(v[row][3]);
    *(ushort4*)(ld + row * 1032 + tid * 4) = o;
  }
  __syncthreads();
#pragma unroll
  for (int s = 0; s < 8; s++) {
    int idx = s * 256 + tid;
    int lf = idx & 63, kt = idx >> 6;
    int row = lf & 15, colb = kt * 32 + ((lf >> 4) << 3);
    *(uint4*)(dst + (kt * 64 + lf) * 8) = *(const uint4*)(ld + row * 1032 + colb);
  }
}

// ---------------------------------------------------------------------------
// k_prep, 576 blocks x 256:
//  [0,512)   : wefft 32(h1) x 64(h2) tile -> frag order (rows h2, k h1)
//  [512,576) : Win fp32 -> bf16 frag
// ---------------------------------------------------------------------------
__global__ __launch_bounds__(256, 4) void k_prep(
    const float* __restrict__ win, const float* __restrict__ wp,
    const float* __restrict__ J, const float* __restrict__ t,
    u16* __restrict__ winfrag, u16* __restrict__ wefrag) {
  __shared__ __align__(16) char smem[33024];
  const int blk = blockIdx.x;
  const int tid = threadIdx.x;
  const int lane = tid & 63;

  if (blk < 512) {
    float* lt = (float*)smem;  // [32][68]  lt[h1l][h2l]
    float wv, alpha;
    wave_scalars(J, t, &wv, &alpha);
    float wLO[8];
#pragma unroll
    for (int p = 0; p < 8; p++)
      wLO[p] = __shfl(wv, (lane & 56) | p) * (1.0f - alpha);
    const int a0 = (blk & 31) * 32;  // h1 base
    const int b0 = (blk >> 5) * 64;  // h2 base
    f32x4 v[2][8];
#pragma unroll
    for (int s = 0; s < 2; s++) {
      const int item = s * 256 + tid;
      const int row = item >> 4, ch = item & 15;
      const float* base = wp + (size_t)(a0 + row) * 1024 + b0 + ch * 4;
#pragma unroll
      for (int j = 0; j < 8; j++) v[s][j] = ld4(base + (size_t)j * 1048576);
    }
#pragma unroll
    for (int s = 0; s < 2; s++) {
      const int item = s * 256 + tid;
      const int row = item >> 4, ch = item & 15;
      f32x4 acc = {0.f, 0.f, 0.f, 0.f};
#pragma unroll
      for (int j = 0; j < 8; j++) acc += wLO[j] * v[s][j];
      *(f32x4*)&lt[row * 68 + ch * 4] = acc;
    }
    __syncthreads();
    {
      const int lf = tid & 63, rtl = tid >> 6;
      const int rowh2 = rtl * 16 + (lf & 15);
      const int kh1 = (lf >> 4) << 3;
      __align__(16) u16 o[8];
#pragma unroll
      for (int i = 0; i < 8; i++)
        o[i] = f32_to_bf16_rne(lt[(kh1 + i) * 68 + rowh2]);
      const int rt = (b0 >> 4) + rtl, kt = a0 >> 5;
      *(uint4*)(wefrag + ((size_t)(rt * 32 + kt) * 64 + lf) * 8) = *(const uint4*)o;
    }
  } else {
    const int cid = blk - 512;  // 64 blocks
    convert16(win + (size_t)cid * 16384, winfrag + (size_t)cid * 16384,
              (u16*)smem, tid);
  }
}

// ---------------------------------------------------------------------------
// k_mid, 640 blocks x 256:
//  [0,512)   : gemm0  wct frag = wefrag(h2) x winfrag(d), K=1024,
//              tiles 64(h2) x 32(d), XCD-swizzled. Epilogue -> B-frag order.
//  [512,640) : x fp32 -> bf16 frag
// ---------------------------------------------------------------------------
__global__ __launch_bounds__(256, 4) void k_mid(
    const float* __restrict__ x, const u16* __restrict__ Af,
    const u16* __restrict__ Bf, u16* __restrict__ xfrag,
    u16* __restrict__ ofrag) {
  __shared__ __align__(16) char smem[33024];
  const int blk = blockIdx.x;
  const int tid = threadIdx.x;

  if (blk < 512) {
    u16* ct = (u16*)smem;  // [64][36]
    const int wave = tid >> 6, lane = tid & 63;
    const int quad = lane >> 4, t16 = lane & 15;
    const int xcd = blk & 7, i = blk >> 3;
    const int m0 = (xcd + 8 * (i & 1)) * 64;  // h2
    const int n0 = (i >> 1) * 32;             // d
    const u16* ap = Af + ((size_t)((m0 + wave * 16) >> 4) * 32) * 512 + lane * 8;
    const u16* bp = Bf + ((size_t)(n0 >> 4) * 32) * 512 + lane * 8;

    f32x4 acc[2] = {{0.f, 0.f, 0.f, 0.f}, {0.f, 0.f, 0.f, 0.f}};
    for (int kb = 0; kb < 32; kb += 4) {
      bf16x8 a[4], b0[4], b1[4];
#pragma unroll
      for (int u = 0; u < 4; u++) {
        a[u] = *(const bf16x8*)(ap + (kb + u) * 512);
        b0[u] = *(const bf16x8*)(bp + (kb + u) * 512);
        b1[u] = *(const bf16x8*)(bp + (32 + kb + u) * 512);
      }
#pragma unroll
      for (int u = 0; u < 4; u++) {
        acc[0] = __builtin_amdgcn_mfma_f32_16x16x32_bf16(a[u], b0[u], acc[0], 0, 0, 0);
        acc[1] = __builtin_amdgcn_mfma_f32_16x16x32_bf16(a[u], b1[u], acc[1], 0, 0, 0);
      }
    }
#pragma unroll
    for (int r = 0; r < 4; r++)
#pragma unroll
      for (int ni = 0; ni < 2; ni++)
        ct[(wave * 16 + quad * 4 + r) * 36 + ni * 16 + t16] =
            f32_to_bf16_rne(acc[ni][r]);
    __syncthreads();
    {
      int lf = tid & 63, rtl = tid >> 6;
      int rowl = rtl * 16 + (lf & 15);
      int colb = (lf >> 4) << 3;
      __align__(16) u16 o[8];
#pragma unroll
      for (int i2 = 0; i2 < 8; i2++) o[i2] = ct[rowl * 36 + colb + i2];
      *(uint4*)(ofrag +
                ((size_t)(((m0 >> 4) + rtl) * 32 + (n0 >> 5)) * 64 + lf) * 8) =
          *(const uint4*)o;
    }
  } else {
    const int cid = blk - 512;  // 128 blocks
    convert16(x + (size_t)cid * 16384, xfrag + (size_t)cid * 16384, (u16*)smem,
              tid);
  }
}

// ---------------------------------------------------------------------------
// k_main: out[b][h2] = (x@wct frag GEMM) + sum_p wHI[p]*coh[b][p][h2].
// 512 blocks x 512 thr, XCD-swizzled. Waves 0-3 GEMM, waves 4-7 stream coh
// (two 16-deep cached-load bursts) -> LDS. One barrier, merged store.
// ---------------------------------------------------------------------------
__global__ __launch_bounds__(512, 4) void k_main(
    const u16* __restrict__ Af, const u16* __restrict__ Bf,
    const float* __restrict__ coh, const float* __restrict__ J,
    const float* __restrict__ t, float* __restrict__ out) {
  __shared__ float cs_lds[64 * 68];
  const int tid = threadIdx.x;
  const int wave = tid >> 6, lane = tid & 63;
  const int xcd = blockIdx.x & 7, i = blockIdx.x >> 3;
  const int m0 = (xcd + 8 * (i >> 4)) * 64;  // b tile
  const int n0 = (i & 15) * 64;              // h2 tile
  const int quad = lane >> 4, t16 = lane & 15;
  const int wm = (wave >> 1) * 32, wn = (wave & 1) * 32;

  f32x4 acc[2][2];
  if (wave < 4) {
    const u16* ap = Af + ((size_t)((m0 + wm) >> 4) * 32) * 512 + lane * 8;
    const u16* bp = Bf + ((size_t)((n0 + wn) >> 4) * 32) * 512 + lane * 8;
#pragma unroll
    for (int mi = 0; mi < 2; mi++)
#pragma unroll
      for (int ni = 0; ni < 2; ni++) acc[mi][ni] = (f32x4){0.f, 0.f, 0.f, 0.f};
    for (int kb = 0; kb < 32; kb += 4) {
      bf16x8 a0[4], a1[4], b0[4], b1[4];
#pragma unroll
      for (int u = 0; u < 4; u++) {
        a0[u] = *(const bf16x8*)(ap + (kb + u) * 512);
        a1[u] = *(const bf16x8*)(ap + (32 + kb + u) * 512);
        b0[u] = *(const bf16x8*)(bp + (kb + u) * 512);
        b1[u] = *(const bf16x8*)(bp + (32 + kb + u) * 512);
      }
#pragma unroll
      for (int u = 0; u < 4; u++) {
        acc[0][0] = __builtin_amdgcn_mfma_f32_16x16x32_bf16(a0[u], b0[u], acc[0][0], 0, 0, 0);
        acc[0][1] = __builtin_amdgcn_mfma_f32_16x16x32_bf16(a0[u], b1[u], acc[0][1], 0, 0, 0);
        acc[1][0] = __builtin_amdgcn_mfma_f32_16x16x32_bf16(a1[u], b0[u], acc[1][0], 0, 0, 0);
        acc[1][1] = __builtin_amdgcn_mfma_f32_16x16x32_bf16(a1[u], b1[u], acc[1][1], 0, 0, 0);
      }
    }
  } else {
    float wv, alpha;
    wave_scalars(J, t, &wv, &alpha);
    float wHI[8];
#pragma unroll
    for (int p = 0; p < 8; p++) wHI[p] = __shfl(wv, (lane & 56) | p) * alpha;
    const int tc = (wave - 4) * 64 + lane;  // 0..255
    const int c4 = tc & 15;                 // 16B chunk within 64 cols
    const int rb = tc >> 4;                 // base row 0..15
    const float* cb = coh + (size_t)m0 * 8192 + n0 + c4 * 4;
#pragma unroll
    for (int up = 0; up < 2; up++) {  // 16 loads in flight per burst
      f32x4 v[2][8];
#pragma unroll
      for (int h = 0; h < 2; h++) {
        const float* cr = cb + (size_t)(rb + 16 * (up * 2 + h)) * 8192;
#pragma unroll
        for (int p = 0; p < 8; p++) v[h][p] = ld4(cr + p * 1024);
      }
#pragma unroll
      for (int h = 0; h < 2; h++) {
        f32x4 a4 = {0.f, 0.f, 0.f, 0.f};
#pragma unroll
        for (int p = 0; p < 8; p++) a4 += wHI[p] * v[h][p];
        *(f32x4*)&cs_lds[(rb + 16 * (up * 2 + h)) * 68 + c4 * 4] = a4;
      }
    }
  }
  __syncthreads();
  if (wave < 4) {
#pragma unroll
    for (int mi = 0; mi < 2; mi++)
#pragma unroll
      for (int r = 0; r < 4; r++) {
        const int ml = wm + mi * 16 + quad * 4 + r;
        const size_t mrow = (size_t)(m0 + ml) * 1024;
#pragma unroll
        for (int ni = 0; ni < 2; ni++) {
          const int nl = wn + ni * 16 + t16;
          out[mrow + n0 + nl] = acc[mi][ni][r] + cs_lds[ml * 68 + nl];
        }
      }
  }
}

// ---------------------------------------------------------------------------
extern "C" void kernel_launch(void* const* d_in, const int* in_sizes, int n_in,
                              void* d_out, int out_size, void* d_ws, size_t ws_size,
                              hipStream_t stream) {
  const float* x   = (const float*)d_in[0];  // [2048,1024]
  const float* win = (const float*)d_in[1];  // [1024,1024]
  const float* wp  = (const float*)d_in[2];  // [8,1024,1024]
  const float* J   = (const float*)d_in[3];  // [8,8]
  const float* coh = (const float*)d_in[4];  // [2048,8,1024]
  const float* t   = (const float*)d_in[5];  // [1]
  float* out = (float*)d_out;                // [2048,1024] fp32

  char* ws = (char*)d_ws;
  u16* xfrag   = (u16*)ws;                         // 4 MB, rt=b/16,  kt=d/32
  u16* winfrag = (u16*)(ws + 4u * 1024 * 1024);    // 2 MB, rt=d/16,  kt=h1/32
  u16* wefrag  = (u16*)(ws + 6u * 1024 * 1024);    // 2 MB, rt=h2/16, kt=h1/32
  u16* wctfrag = (u16*)(ws + 8u * 1024 * 1024);    // 2 MB, rt=h2/16, kt=d/32

  // wefft build + win convert
  k_prep<<<576, 256, 0, stream>>>(win, wp, J, t, winfrag, wefrag);
  // wct[h2][d] = sum_h1 weff[h2][h1]*win[d][h1]  (+ x convert riding along)
  k_mid<<<640, 256, 0, stream>>>(x, wefrag, winfrag, xfrag, wctfrag);
  // out[b][h2] = sum_d x[b][d]*wct[h2][d] + sum_p wHI[p]*coh[b][p][h2]
  k_main<<<512, 512, 0, stream>>>(xfrag, wctfrag, coh, J, t, out);
}